// Round 3
// baseline (1270.434 us; speedup 1.0000x reference)
//
#include <hip/hip_runtime.h>
#include <hip/hip_bf16.h>

using bf16 = __hip_bfloat16;

#define NPTS 1056   // 32 nodes + 1024 edges
#define LAT_ 1536
#define UNIT_ 512

// ---------------- sampling: S[b][c][m] fp32, m in [0,1056) ----------------
__global__ __launch_bounds__(256) void sample_k(
    const float* __restrict__ f0, const float* __restrict__ f1, const float* __restrict__ f2,
    const float* __restrict__ f3, const float* __restrict__ f4, const float* __restrict__ f5,
    const float* __restrict__ P, float* __restrict__ S) {
  int m = blockIdx.x * 256 + threadIdx.x;
  if (m >= NPTS) return;
  int c = blockIdx.y, b = blockIdx.z;
  float px, py;
  if (m < 32) {
    px = P[(b*32 + m)*2 + 0];
    py = P[(b*32 + m)*2 + 1];
  } else {
    int ij = m - 32, i = ij >> 5, j = ij & 31;
    px = 0.5f*(P[(b*32+i)*2+0] + P[(b*32+j)*2+0]);
    py = 0.5f*(P[(b*32+i)*2+1] + P[(b*32+j)*2+1]);
  }
  const float* f; int W, cl, C;
  if (c < 64)       { f = f0; W = 128; cl = c;       C = 64; }
  else if (c < 128) { f = f1; W = 64;  cl = c-64;    C = 64; }
  else if (c < 256) { f = f2; W = 32;  cl = c-128;   C = 128; }
  else if (c < 512) { f = f3; W = 16;  cl = c-256;   C = 256; }
  else if (c < 1024){ f = f4; W = 8;   cl = c-512;   C = 512; }
  else              { f = f5; W = 1;   cl = c-1024;  C = 512; }
  // grid_sample align_corners=False + border clamp:  x = px*W/256 - 0.5, clamped
  float fx = px * ((float)W * (1.0f/256.0f)) - 0.5f;
  float fy = py * ((float)W * (1.0f/256.0f)) - 0.5f;
  fx = fminf(fmaxf(fx, 0.f), (float)(W-1));
  fy = fminf(fmaxf(fy, 0.f), (float)(W-1));
  float x0f = floorf(fx), y0f = floorf(fy);
  float wx = fx - x0f, wy = fy - y0f;
  int x0 = (int)x0f, y0 = (int)y0f;
  int x1 = min(x0+1, W-1), y1 = min(y0+1, W-1);
  const float* pl = f + (long)(b*C + cl) * W * W;
  float v00 = pl[y0*W+x0], v01 = pl[y0*W+x1];
  float v10 = pl[y1*W+x0], v11 = pl[y1*W+x1];
  float v = v00*(1.f-wx)*(1.f-wy) + v01*wx*(1.f-wy) + v10*(1.f-wx)*wy + v11*wx*wy;
  S[((long)b*LAT_ + c)*NPTS + m] = v;
}

// ---------------- BN constants: scale = bg/sqrt(bv+1e-5), shift = bb - bm*scale
__global__ void bnconst_k(const float* g_bg, const float* g_bb, const float* g_bm, const float* g_bv,
                          const float* p_bg, const float* p_bb, const float* p_bm, const float* p_bv,
                          float* out) {
  int k = blockIdx.x * 256 + threadIdx.x;
  if (k >= 512) return;
  float sg = g_bg[k] / sqrtf(g_bv[k] + 1e-5f);
  out[k]       = sg;
  out[512+k]   = g_bb[k] - g_bm[k] * sg;
  float sp = p_bg[k] / sqrtf(p_bv[k] + 1e-5f);
  out[1024+k]  = sp;
  out[1536+k]  = p_bb[k] - p_bm[k] * sp;
}

// ---------------- generic 64x64 tiled GEMM: C[b][o][m] = sum_k W[o][k]*S[b][k][m]
// MODE 0: plain (+bias if non-null)
// MODE 1: intro-edge epilogue: + Ai[b][o][i] + Aj[b][o][j] + bias[o]   (m == ij)
// MODE 2: chorus: A-operand = relu(S*bnscale + bnshift); epilogue: + S[o][m] + bias[o]
template<int MODE>
__global__ __launch_bounds__(256) void gemm_k(
    const float* __restrict__ W_, int ldw,
    const float* __restrict__ S, int ldsm, long sstride,
    float* __restrict__ C_, int ldcm, long cstride,
    int K, int M,
    const float* __restrict__ bias,
    const float* __restrict__ Ai, const float* __restrict__ Aj,
    const float* __restrict__ bnscale, const float* __restrict__ bnshift) {
  int b = blockIdx.z;
  const float* Sb = S + (long)b * sstride;
  float* Cb = C_ + (long)b * cstride;
  int m0 = blockIdx.x * 64, o0 = blockIdx.y * 64;
  __shared__ float Wt[16][68];   // [k][o], padded
  __shared__ float St[16][64];   // [k][m]
  int tid = threadIdx.x;
  int tx = tid & 15, ty = tid >> 4;
  float acc[4][4] = {};
  for (int kb = 0; kb < K; kb += 16) {
    {
      int row = tid >> 2;          // 0..63 (o within tile)
      int kk4 = (tid & 3) * 4;     // 0,4,8,12
      const float* wp = W_ + (long)(o0 + row) * ldw + kb + kk4;
      #pragma unroll
      for (int e = 0; e < 4; ++e) Wt[kk4 + e][row] = wp[e];
    }
    {
      int mm = tid & 63;
      int kr = tid >> 6;           // 0..3
      int gm = m0 + mm;
      #pragma unroll
      for (int r = 0; r < 4; ++r) {
        int kk = kr + r*4;
        float v = (gm < M) ? Sb[(long)(kb+kk)*ldsm + gm] : 0.f;
        if (MODE == 2) v = fmaxf(fmaf(v, bnscale[kb+kk], bnshift[kb+kk]), 0.f);
        St[kk][mm] = v;
      }
    }
    __syncthreads();
    #pragma unroll
    for (int kk = 0; kk < 16; ++kk) {
      float a[4], s[4];
      #pragma unroll
      for (int i = 0; i < 4; ++i) a[i] = Wt[kk][ty*4+i];
      #pragma unroll
      for (int j = 0; j < 4; ++j) s[j] = St[kk][tx*4+j];
      #pragma unroll
      for (int i = 0; i < 4; ++i)
        #pragma unroll
        for (int j = 0; j < 4; ++j)
          acc[i][j] = fmaf(a[i], s[j], acc[i][j]);
    }
    __syncthreads();
  }
  #pragma unroll
  for (int i = 0; i < 4; ++i) {
    int go = o0 + ty*4 + i;
    float bv = bias ? bias[go] : 0.f;
    #pragma unroll
    for (int j = 0; j < 4; ++j) {
      int gm = m0 + tx*4 + j;
      if (gm < M) {
        float v = acc[i][j] + bv;
        if (MODE == 1)
          v += Ai[(long)b*UNIT_*32 + go*32 + (gm>>5)] + Aj[(long)b*UNIT_*32 + go*32 + (gm&31)];
        if (MODE == 2)
          v += Sb[(long)go*ldsm + gm];
        Cb[(long)go*ldcm + gm] = v;
      }
    }
  }
}

// ---------------- final: gate dot + sigmoid, L2 normalize pr, mask, fp32 store
__global__ __launch_bounds__(256) void final_k(
    const float* __restrict__ Yg, const float* __restrict__ PRr,
    const float* __restrict__ g_ow, const float* __restrict__ g_ob,
    const int* __restrict__ n, float* __restrict__ out) {
  int b = blockIdx.y;
  int ij = blockIdx.x * 256 + threadIdx.x;   // 0..1023
  const float* Ygb = Yg + (long)b * UNIT_ * 1024;
  float g = g_ob[0];
  for (int o = 0; o < UNIT_; ++o)
    g = fmaf(g_ow[o], Ygb[o*1024 + ij], g);
  float gate = 1.f / (1.f + expf(-g));
  int i = ij >> 5, j = ij & 31;
  int nb = n[b];
  float maskv = (i < nb && j < nb) ? 1.f : 0.f;
  const float* prb = PRr + (long)b * 64 * 1024;
  float v[64], ss = 0.f;
  #pragma unroll
  for (int c = 0; c < 64; ++c) { float x = prb[c*1024 + ij]; v[c] = x; ss = fmaf(x, x, ss); }
  float scale = gate * maskv / fmaxf(sqrtf(ss), 1e-12f);
  float* ob = out + (long)b * 64 * 1024;
  #pragma unroll
  for (int c = 0; c < 64; ++c) ob[c*1024 + ij] = v[c] * scale;
}

extern "C" void kernel_launch(void* const* d_in, const int* in_sizes, int n_in,
                              void* d_out, int out_size, void* d_ws, size_t ws_size,
                              hipStream_t stream) {
  const float* f0 = (const float*)d_in[0];
  const float* f1 = (const float*)d_in[1];
  const float* f2 = (const float*)d_in[2];
  const float* f3 = (const float*)d_in[3];
  const float* f4 = (const float*)d_in[4];
  const float* f5 = (const float*)d_in[5];
  const float* P  = (const float*)d_in[6];
  const int*  n  = (const int*)d_in[7];
  const float *g_iw=(const float*)d_in[8],  *g_ib=(const float*)d_in[9],
              *g_bg=(const float*)d_in[10], *g_bb=(const float*)d_in[11],
              *g_bm=(const float*)d_in[12], *g_bv=(const float*)d_in[13],
              *g_cw=(const float*)d_in[14], *g_cb=(const float*)d_in[15],
              *g_ow=(const float*)d_in[16], *g_ob=(const float*)d_in[17];
  const float *p_iw=(const float*)d_in[18], *p_ib=(const float*)d_in[19],
              *p_bg=(const float*)d_in[20], *p_bb=(const float*)d_in[21],
              *p_bm=(const float*)d_in[22], *p_bv=(const float*)d_in[23],
              *p_cw=(const float*)d_in[24], *p_cb=(const float*)d_in[25],
              *p_ow=(const float*)d_in[26], *p_ob=(const float*)d_in[27];
  float* out = (float*)d_out;
  float* ws = (float*)d_ws;

  // workspace layout (floats); Y/pr reuse the dead S region
  float* S    = ws;                     // 8*1536*1056 = 12,976,128
  float* Ai_g = ws + 12976128;          // 8*512*32 each
  float* Aj_g = Ai_g + 131072;
  float* Ai_p = Aj_g + 131072;
  float* Aj_p = Ai_p + 131072;
  float* bn   = Aj_p + 131072;          // 2048
  float* Xg   = bn + 2048;              // 8*512*1024
  float* Xp   = Xg + 4194304;           // total peak: 21,891,072 floats = 87.6 MB
  float* Yg   = ws;                     // overlay on S (dead after intro GEMMs)
  float* Yp   = ws + 4194304;
  float* PRr  = ws + 8388608;           // 8*64*1024

  const long sstr = (long)LAT_ * NPTS;        // S batch stride
  const long xstr = (long)UNIT_ * 1024;       // X/Y batch stride

  bnconst_k<<<dim3(2), 256, 0, stream>>>(g_bg, g_bb, g_bm, g_bv, p_bg, p_bb, p_bm, p_bv, bn);
  sample_k<<<dim3(5, 1536, 8), 256, 0, stream>>>(f0, f1, f2, f3, f4, f5, P, S);

  // node projections: [512x1536] x [1536x32] (i-slice and j-slice of iw)
  gemm_k<0><<<dim3(1, 8, 8), 256, 0, stream>>>(g_iw,      4608, S, NPTS, sstr, Ai_g, 32, 16384, 1536, 32, nullptr, nullptr, nullptr, nullptr, nullptr);
  gemm_k<0><<<dim3(1, 8, 8), 256, 0, stream>>>(g_iw+1536, 4608, S, NPTS, sstr, Aj_g, 32, 16384, 1536, 32, nullptr, nullptr, nullptr, nullptr, nullptr);
  gemm_k<0><<<dim3(1, 8, 8), 256, 0, stream>>>(p_iw,      4608, S, NPTS, sstr, Ai_p, 32, 16384, 1536, 32, nullptr, nullptr, nullptr, nullptr, nullptr);
  gemm_k<0><<<dim3(1, 8, 8), 256, 0, stream>>>(p_iw+1536, 4608, S, NPTS, sstr, Aj_p, 32, 16384, 1536, 32, nullptr, nullptr, nullptr, nullptr, nullptr);

  // intro edge GEMM: We @ E + Ai[i] + Aj[j] + ib  -> X
  gemm_k<1><<<dim3(16, 8, 8), 256, 0, stream>>>(g_iw+3072, 4608, S+32, NPTS, sstr, Xg, 1024, xstr, 1536, 1024, g_ib, Ai_g, Aj_g, nullptr, nullptr);
  gemm_k<1><<<dim3(16, 8, 8), 256, 0, stream>>>(p_iw+3072, 4608, S+32, NPTS, sstr, Xp, 1024, xstr, 1536, 1024, p_ib, Ai_p, Aj_p, nullptr, nullptr);

  // chorus: Y = X + cw @ relu(bn(X)) + cb
  gemm_k<2><<<dim3(16, 8, 8), 256, 0, stream>>>(g_cw, 512, Xg, 1024, xstr, Yg, 1024, xstr, 512, 1024, g_cb, nullptr, nullptr, bn,      bn+512);
  gemm_k<2><<<dim3(16, 8, 8), 256, 0, stream>>>(p_cw, 512, Xp, 1024, xstr, Yp, 1024, xstr, 512, 1024, p_cb, nullptr, nullptr, bn+1024, bn+1536);

  // pr outro: [64x512] x [512x1024]
  gemm_k<0><<<dim3(16, 1, 8), 256, 0, stream>>>(p_ow, 512, Yp, 1024, xstr, PRr, 1024, 65536, 512, 1024, p_ob, nullptr, nullptr, nullptr, nullptr);

  // gate + normalize + mask + store
  final_k<<<dim3(4, 8), 256, 0, stream>>>(Yg, PRr, g_ow, g_ob, n, out);
}

// Round 4
// 404.458 us; speedup vs baseline: 3.1411x; 3.1411x over previous
//
#include <hip/hip_runtime.h>
#include <hip/hip_bf16.h>

using bf16 = __hip_bfloat16;
using short8 = __attribute__((ext_vector_type(8))) short;
using f32x4  = __attribute__((ext_vector_type(4))) float;

#define LAT_ 1536
#define UNIT_ 512

// ---------------- weight pack: Wpack[3072][1536] bf16 ----------------
// rows 0-511: g_Wi | 512-1023: g_Wj | 1024-1535: p_Wi | 1536-2047: p_Wj
// rows 2048-2559: g_We | 2560-3071: p_We
__global__ __launch_bounds__(256) void conv1536_k(const float* __restrict__ g_iw,
                                                  const float* __restrict__ p_iw,
                                                  bf16* __restrict__ Wp) {
  int seg = blockIdx.y;
  int idx = blockIdx.x * 256 + threadIdx.x;          // 0 .. 512*1536
  if (idx >= 512 * 1536) return;
  int r = idx / 1536, c = idx % 1536;
  const float* src; int co;
  switch (seg) {
    case 0: src = g_iw; co = 0;    break;
    case 1: src = g_iw; co = 1536; break;
    case 2: src = p_iw; co = 0;    break;
    case 3: src = p_iw; co = 1536; break;
    case 4: src = g_iw; co = 3072; break;
    default: src = p_iw; co = 3072; break;
  }
  Wp[(long)seg * 512 * 1536 + idx] = __float2bfloat16(src[(long)r * 4608 + co + c]);
}

// cwpack: [0]=g_cw (512x512), [+262144]=p_cw, [+524288]=p_ow (64x512)
__global__ __launch_bounds__(256) void conv512_k(const float* __restrict__ g_cw,
                                                 const float* __restrict__ p_cw,
                                                 const float* __restrict__ p_ow,
                                                 bf16* __restrict__ dst) {
  int seg = blockIdx.y;
  int idx = blockIdx.x * 256 + threadIdx.x;
  int lim = (seg == 2) ? 64 * 512 : 512 * 512;
  if (idx >= lim) return;
  const float* s = seg == 0 ? g_cw : (seg == 1 ? p_cw : p_ow);
  long off = (long)seg * 262144;
  dst[off + idx] = __float2bfloat16(s[idx]);
}

// ---------------- BN constants ----------------
__global__ void bnconst_k(const float* g_bg, const float* g_bb, const float* g_bm, const float* g_bv,
                          const float* p_bg, const float* p_bb, const float* p_bm, const float* p_bv,
                          float* out) {
  int k = blockIdx.x * 256 + threadIdx.x;
  if (k >= 512) return;
  float sg = g_bg[k] / sqrtf(g_bv[k] + 1e-5f);
  out[k]        = sg;
  out[512 + k]  = g_bb[k] - g_bm[k] * sg;
  float sp = p_bg[k] / sqrtf(p_bv[k] + 1e-5f);
  out[1024 + k] = sp;
  out[1536 + k] = p_bb[k] - p_bm[k] * sp;
}

// ---------------- sampling: Sb[b][m=1056][k=1536] bf16, k-contiguous ----------------
template<int C, int W>
__device__ __forceinline__ void proc_level(
    const float* __restrict__ f, int b, int p0,
    const float* MX, const float* MY, bf16* __restrict__ Sb, int koff, int t) {
  const int ITEMS = 16 * C;
  for (int idx = t; idx < ITEMS; idx += 256) {
    int q = idx / C, c = idx % C;                    // C is pow2 -> shifts
    float x = MX[q], y = MY[q];
    float fx = fminf(fmaxf(x * ((float)W / 256.0f) - 0.5f, 0.f), (float)(W - 1));
    float fy = fminf(fmaxf(y * ((float)W / 256.0f) - 0.5f, 0.f), (float)(W - 1));
    float x0f = floorf(fx), y0f = floorf(fy);
    float wx = fx - x0f, wy = fy - y0f;
    int x0 = (int)x0f, y0 = (int)y0f;
    int x1 = min(x0 + 1, W - 1), y1 = min(y0 + 1, W - 1);
    const float* pl = f + (long)(b * C + c) * (W * W);
    float v00 = pl[y0 * W + x0], v01 = pl[y0 * W + x1];
    float v10 = pl[y1 * W + x0], v11 = pl[y1 * W + x1];
    float v = v00 * (1.f - wx) * (1.f - wy) + v01 * wx * (1.f - wy)
            + v10 * (1.f - wx) * wy + v11 * wx * wy;
    Sb[(long)(p0 + q) * LAT_ + koff + c] = __float2bfloat16(v);
  }
}

__global__ __launch_bounds__(256) void sample2_k(
    const float* __restrict__ f0, const float* __restrict__ f1, const float* __restrict__ f2,
    const float* __restrict__ f3, const float* __restrict__ f4, const float* __restrict__ f5,
    const float* __restrict__ P, bf16* __restrict__ Sball) {
  int b = blockIdx.y, p0 = blockIdx.x * 16, t = threadIdx.x;
  __shared__ float Px[32], Py[32], MX[16], MY[16];
  if (t < 32) { Px[t] = P[(b * 32 + t) * 2]; Py[t] = P[(b * 32 + t) * 2 + 1]; }
  __syncthreads();
  if (t < 16) {
    int m = p0 + t;
    float x, y;
    if (m < 32) { x = Px[m]; y = Py[m]; }
    else { int ij = m - 32, i = ij >> 5, j = ij & 31;
           x = 0.5f * (Px[i] + Px[j]); y = 0.5f * (Py[i] + Py[j]); }
    MX[t] = x; MY[t] = y;
  }
  __syncthreads();
  bf16* Sb = Sball + (long)b * 1056 * LAT_;
  proc_level<64, 128>(f0, b, p0, MX, MY, Sb, 0,    t);
  proc_level<64, 64 >(f1, b, p0, MX, MY, Sb, 64,   t);
  proc_level<128, 32>(f2, b, p0, MX, MY, Sb, 128,  t);
  proc_level<256, 16>(f3, b, p0, MX, MY, Sb, 256,  t);
  proc_level<512, 8 >(f4, b, p0, MX, MY, Sb, 512,  t);
  proc_level<512, 1 >(f5, b, p0, MX, MY, Sb, 1024, t);
}

// ---------------- node GEMM: A4[b][m=32][vo=2048] = Sb_nodes @ Wpack[0:2048]^T ----------------
__global__ __launch_bounds__(256) void nodegemm_k(
    const bf16* __restrict__ Sball, const bf16* __restrict__ Wp, float* __restrict__ A4) {
  int b = blockIdx.y;
  int n0 = blockIdx.x * 64;
  int t = threadIdx.x, w = t >> 6, lane = t & 63;
  int nn = n0 + w * 16;
  int frow = lane & 15, fko = (lane >> 4) * 8;
  const bf16* Ab = Sball + (long)b * 1056 * LAT_;
  f32x4 acc[2] = {};
  for (int kb = 0; kb < LAT_; kb += 32) {
    short8 bq = *(const short8*)&Wp[(long)(nn + frow) * LAT_ + kb + fko];
    #pragma unroll
    for (int i = 0; i < 2; ++i) {
      short8 aq = *(const short8*)&Ab[(long)(i * 16 + frow) * LAT_ + kb + fko];
      acc[i] = __builtin_amdgcn_mfma_f32_16x16x32_bf16(aq, bq, acc[i], 0, 0, 0);
    }
  }
  #pragma unroll
  for (int i = 0; i < 2; ++i)
    #pragma unroll
    for (int r = 0; r < 4; ++r) {
      int m = i * 16 + (lane >> 4) * 4 + r;
      int n = nn + (lane & 15);
      A4[(long)b * 65536 + m * 2048 + n] = acc[i][r];
    }
}

// ---------------- main MFMA GEMM: acc[m][n] = sum_k A[m][k] * Bw[n][k] ----------------
// MODE 0 edge : +bias[n] +A4[i][seli+n] +A4[j][selj+n]; Df=X fp32 [m][512];
//               Dh = bf16(relu(val*bnsc[n]+bnsh[n])) [m][512]
// MODE 1 chorus-g : +bias[n] +resid[m][n] -> Df fp32
// MODE 2 chorus-p : +bias[n] +resid[m][n] -> Dh bf16
// MODE 3 outro    : +bias[n] -> Df fp32 [m][Ntot]
#define BM 128
#define BN 64
#define BK 32
template<int MODE>
__global__ __launch_bounds__(256) void mgemm_k(
    const bf16* __restrict__ A, int lda, long astride,
    const bf16* __restrict__ Bw, int ldb, int K, int Mtot, int Ntot,
    const float* __restrict__ bias,
    const float* __restrict__ A4, int seli, int selj,
    const float* __restrict__ bnsc, const float* __restrict__ bnsh,
    const float* __restrict__ resid,
    float* __restrict__ Df, bf16* __restrict__ Dh) {
  int b = blockIdx.z;
  const bf16* Ab = A + (long)b * astride;
  int m0 = blockIdx.x * BM, n0 = blockIdx.y * BN;
  __shared__ bf16 Ash[BM][BK + 8];
  __shared__ bf16 Bsh[BN][BK + 8];
  int t = threadIdx.x;
  int w = t >> 6, lane = t & 63;
  int mq = w * 32;                                   // wave handles 32 m-rows
  int frow = lane & 15, fko = (lane >> 4) * 8;
  f32x4 acc[2][4] = {};
  for (int kb = 0; kb < K; kb += BK) {
    #pragma unroll
    for (int q = 0; q < 2; ++q) {                    // stage A 128x32
      int flat = q * 256 + t;
      int r = flat >> 2, ko = (flat & 3) * 8;
      *(uint4*)&Ash[r][ko] = *(const uint4*)&Ab[(long)(m0 + r) * lda + kb + ko];
    }
    {                                                // stage B 64x32
      int r = t >> 2, ko = (t & 3) * 8;
      *(uint4*)&Bsh[r][ko] = *(const uint4*)&Bw[(long)(n0 + r) * ldb + kb + ko];
    }
    __syncthreads();
    short8 af[2], bq[4];
    #pragma unroll
    for (int i = 0; i < 2; ++i) af[i] = *(const short8*)&Ash[mq + i * 16 + frow][fko];
    #pragma unroll
    for (int j = 0; j < 4; ++j) bq[j] = *(const short8*)&Bsh[j * 16 + frow][fko];
    #pragma unroll
    for (int i = 0; i < 2; ++i)
      #pragma unroll
      for (int j = 0; j < 4; ++j)
        acc[i][j] = __builtin_amdgcn_mfma_f32_16x16x32_bf16(af[i], bq[j], acc[i][j], 0, 0, 0);
    __syncthreads();
  }
  #pragma unroll
  for (int i = 0; i < 2; ++i) {
    #pragma unroll
    for (int j = 0; j < 4; ++j) {
      #pragma unroll
      for (int r = 0; r < 4; ++r) {
        int m = m0 + mq + i * 16 + (lane >> 4) * 4 + r;
        int n = n0 + j * 16 + (lane & 15);
        float v = acc[i][j][r] + bias[n];
        if (MODE == 0) {
          v += A4[(long)b * 65536 + (m >> 5) * 2048 + seli + n]
             + A4[(long)b * 65536 + (m & 31) * 2048 + selj + n];
          Df[((long)b * Mtot + m) * 512 + n] = v;
          float d = fmaxf(fmaf(v, bnsc[n], bnsh[n]), 0.f);
          Dh[((long)b * Mtot + m) * 512 + n] = __float2bfloat16(d);
        } else if (MODE == 1) {
          v += resid[((long)b * Mtot + m) * 512 + n];
          Df[((long)b * Mtot + m) * 512 + n] = v;
        } else if (MODE == 2) {
          v += resid[((long)b * Mtot + m) * 512 + n];
          Dh[((long)b * Mtot + m) * 512 + n] = __float2bfloat16(v);
        } else {
          Df[((long)b * Mtot + m) * Ntot + n] = v;
        }
      }
    }
  }
}

// ---------------- final: wave per (b, ij) ----------------
__global__ __launch_bounds__(256) void final2_k(
    const float* __restrict__ Yg, const float* __restrict__ PR,
    const float* __restrict__ g_ow, const float* __restrict__ g_ob,
    const int* __restrict__ n, float* __restrict__ out) {
  int gw = blockIdx.x * 4 + (threadIdx.x >> 6);      // 0..8191
  int lane = threadIdx.x & 63;
  int b = gw >> 10, ij = gw & 1023;
  const float* yrow = Yg + ((long)b * 1024 + ij) * 512;
  float g = 0.f;
  #pragma unroll
  for (int q = 0; q < 8; ++q) { int o = q * 64 + lane; g = fmaf(g_ow[o], yrow[o], g); }
  #pragma unroll
  for (int off = 32; off; off >>= 1) g += __shfl_down(g, off);
  g = __shfl(g, 0) + g_ob[0];
  float gate = 1.f / (1.f + expf(-g));
  int i = ij >> 5, j = ij & 31, nb = n[b];
  float maskv = (i < nb && j < nb) ? 1.f : 0.f;
  float v = PR[((long)b * 1024 + ij) * 64 + lane];
  float ss = v * v;
  #pragma unroll
  for (int off = 32; off; off >>= 1) ss += __shfl_down(ss, off);
  ss = __shfl(ss, 0);
  float scale = gate * maskv / fmaxf(sqrtf(ss), 1e-12f);
  out[((long)b * 64 + lane) * 1024 + ij] = v * scale;
}

extern "C" void kernel_launch(void* const* d_in, const int* in_sizes, int n_in,
                              void* d_out, int out_size, void* d_ws, size_t ws_size,
                              hipStream_t stream) {
  const float* f0 = (const float*)d_in[0];
  const float* f1 = (const float*)d_in[1];
  const float* f2 = (const float*)d_in[2];
  const float* f3 = (const float*)d_in[3];
  const float* f4 = (const float*)d_in[4];
  const float* f5 = (const float*)d_in[5];
  const float* P  = (const float*)d_in[6];
  const int*   n  = (const int*)d_in[7];
  const float *g_iw=(const float*)d_in[8],  *g_ib=(const float*)d_in[9],
              *g_bg=(const float*)d_in[10], *g_bb=(const float*)d_in[11],
              *g_bm=(const float*)d_in[12], *g_bv=(const float*)d_in[13],
              *g_cw=(const float*)d_in[14], *g_cb=(const float*)d_in[15],
              *g_ow=(const float*)d_in[16], *g_ob=(const float*)d_in[17];
  const float *p_iw=(const float*)d_in[18], *p_ib=(const float*)d_in[19],
              *p_cw=(const float*)d_in[24], *p_cb=(const float*)d_in[25],
              *p_ow=(const float*)d_in[26], *p_ob=(const float*)d_in[27];
  const float *p_bg=(const float*)d_in[20], *p_bb=(const float*)d_in[21],
              *p_bm=(const float*)d_in[22], *p_bv=(const float*)d_in[23];
  float* out = (float*)d_out;
  char* wsb = (char*)d_ws;

  // workspace layout (bytes)
  bf16*  Sb    = (bf16*)(wsb + 0);                    // 8*1056*1536*2 = 25,952,256
  bf16*  Wp    = (bf16*)(wsb + 25952256);             // 3072*1536*2   =  9,437,184
  bf16*  CWp   = (bf16*)(wsb + 35389440);             // g_cw|p_cw|p_ow bf16 = 1,114,112
  float* bn    = (float*)(wsb + 36503552);            // 2048*4
  float* A4    = (float*)(wsb + 36511744);            // 8*32*2048*4   =  2,097,152
  float* X     = (float*)(wsb + 38608896);            // 8*1024*512*4  = 16,777,216 (g then p)
  bf16*  D16   = (bf16*)(wsb + 55386112);             // 8*1024*512*2  =  8,388,608 (g then p)
  float* Yg    = (float*)(wsb + 63774720);            // 16,777,216            -> ends 80,551,936
  bf16*  Yp16  = (bf16*)(wsb + 0);                    // overlay on Sb (dead)
  float* PR    = A4;                                  // overlay on A4 (dead)

  bf16* gcw16 = CWp;
  bf16* pcw16 = CWp + 262144;
  bf16* pow16 = CWp + 524288;

  conv1536_k<<<dim3(3072, 6), 256, 0, stream>>>(g_iw, p_iw, Wp);
  conv512_k<<<dim3(1024, 3), 256, 0, stream>>>(g_cw, p_cw, p_ow, CWp);
  bnconst_k<<<dim3(2), 256, 0, stream>>>(g_bg, g_bb, g_bm, g_bv, p_bg, p_bb, p_bm, p_bv, bn);
  sample2_k<<<dim3(66, 8), 256, 0, stream>>>(f0, f1, f2, f3, f4, f5, P, Sb);

  // node projections: A4[b][32][2048]
  nodegemm_k<<<dim3(32, 8), 256, 0, stream>>>(Sb, Wp, A4);

  const long astr_S = (long)1056 * LAT_;
  const long astr_X = (long)1024 * 512;

  // edge-g: X, D16  (A = Sb edge rows, B = g_We)
  mgemm_k<0><<<dim3(8, 8, 8), 256, 0, stream>>>(
      Sb + 32 * LAT_, LAT_, astr_S, Wp + (long)2048 * LAT_, LAT_, LAT_, 1024, 512,
      g_ib, A4, 0, 512, bn, bn + 512, nullptr, X, D16);
  // chorus-g: Yg = X + g_cw @ relu(bn(X)) + g_cb
  mgemm_k<1><<<dim3(8, 8, 8), 256, 0, stream>>>(
      D16, 512, astr_X, gcw16, 512, 512, 1024, 512,
      g_cb, nullptr, 0, 0, nullptr, nullptr, X, Yg, nullptr);
  // edge-p: X, D16 (reuse buffers)
  mgemm_k<0><<<dim3(8, 8, 8), 256, 0, stream>>>(
      Sb + 32 * LAT_, LAT_, astr_S, Wp + (long)2560 * LAT_, LAT_, LAT_, 1024, 512,
      p_ib, A4, 1024, 1536, bn + 1024, bn + 1536, nullptr, X, D16);
  // chorus-p: Yp16 = bf16(X + p_cw @ relu(bn(X)) + p_cb)   (overlay on Sb region)
  mgemm_k<2><<<dim3(8, 8, 8), 256, 0, stream>>>(
      D16, 512, astr_X, pcw16, 512, 512, 1024, 512,
      p_cb, nullptr, 0, 0, nullptr, nullptr, X, nullptr, Yp16);
  // outro: PR[b][1024][64] = Yp @ p_ow^T + p_ob   (overlay on A4 region)
  mgemm_k<3><<<dim3(8, 1, 8), 256, 0, stream>>>(
      Yp16, 512, astr_X, pow16, 512, 512, 1024, 64,
      p_ob, nullptr, 0, 0, nullptr, nullptr, nullptr, PR, nullptr);

  final2_k<<<dim3(2048), 256, 0, stream>>>(Yg, PR, g_ow, g_ob, n, out);
}

// Round 5
// 296.414 us; speedup vs baseline: 4.2860x; 1.3645x over previous
//
#include <hip/hip_runtime.h>
#include <hip/hip_bf16.h>

using bf16 = __hip_bfloat16;
using short8 = __attribute__((ext_vector_type(8))) short;
using f32x4  = __attribute__((ext_vector_type(4))) float;
typedef unsigned int u32;

#define LAT_ 1536

// ---- async global->LDS 16B (lane-contiguous LDS dest, m97 pattern) ----
__device__ __forceinline__ void glds16(const bf16* g, bf16* l) {
  __builtin_amdgcn_global_load_lds(
      (const __attribute__((address_space(1))) void*)g,
      (__attribute__((address_space(3))) void*)l, 16, 0, 0);
}

// ---------------- weight pack: Wp[3072][1536] bf16 ----------------
// rows 0-511 g_Wi | 512-1023 g_Wj | 1024-1535 p_Wi | 1536-2047 p_Wj | 2048-2559 g_We | 2560-3071 p_We
__global__ __launch_bounds__(256) void conv1536_k(const float* __restrict__ g_iw,
                                                  const float* __restrict__ p_iw,
                                                  bf16* __restrict__ Wp) {
  int seg = blockIdx.y;
  int idx = blockIdx.x * 256 + threadIdx.x;
  if (idx >= 512 * 1536) return;
  int r = idx / 1536, c = idx % 1536;
  const float* src; int co;
  switch (seg) {
    case 0: src = g_iw; co = 0;    break;
    case 1: src = g_iw; co = 1536; break;
    case 2: src = p_iw; co = 0;    break;
    case 3: src = p_iw; co = 1536; break;
    case 4: src = g_iw; co = 3072; break;
    default: src = p_iw; co = 3072; break;
  }
  Wp[(long)seg * 512 * 1536 + idx] = __float2bfloat16(src[(long)r * 4608 + co + c]);
}

// CWp: g_cw(262144) | p_cw(262144) | p_ow(32768) | T5 bf16 (4096)
__global__ __launch_bounds__(256) void conv512_k(const float* __restrict__ g_cw,
                                                 const float* __restrict__ p_cw,
                                                 const float* __restrict__ p_ow,
                                                 const float* __restrict__ f5,
                                                 bf16* __restrict__ dst) {
  int seg = blockIdx.y;
  int idx = blockIdx.x * 256 + threadIdx.x;
  int lim = (seg < 2) ? 262144 : (seg == 2 ? 32768 : 4096);
  if (idx >= lim) return;
  const float* s = seg == 0 ? g_cw : (seg == 1 ? p_cw : (seg == 2 ? p_ow : f5));
  long off = seg == 0 ? 0 : (seg == 1 ? 262144 : (seg == 2 ? 524288 : 557056));
  dst[off + idx] = __float2bfloat16(s[idx]);
}

// bnpack: [0:512) g-scale [512:1024) g-shift [1024:1536) p-scale [1536:2048) p-shift
//         [2048:2560) g_ib [2560:3072) p_ib [3072:3584) g_cb [3584:4096) p_cb
__global__ void bnconst2_k(const float* g_bg, const float* g_bb, const float* g_bm, const float* g_bv,
                           const float* p_bg, const float* p_bb, const float* p_bm, const float* p_bv,
                           const float* g_ib, const float* p_ib, const float* g_cb, const float* p_cb,
                           float* bn) {
  int k = blockIdx.x * 256 + threadIdx.x;
  if (k >= 512) return;
  float sg = g_bg[k] / sqrtf(g_bv[k] + 1e-5f);
  bn[k] = sg; bn[512 + k] = g_bb[k] - g_bm[k] * sg;
  float sp = p_bg[k] / sqrtf(p_bv[k] + 1e-5f);
  bn[1024 + k] = sp; bn[1536 + k] = p_bb[k] - p_bm[k] * sp;
  bn[2048 + k] = g_ib[k]; bn[2560 + k] = p_ib[k];
  bn[3072 + k] = g_cb[k]; bn[3584 + k] = p_cb[k];
}

// ---------------- NCHW fp32 -> NHWC bf16 transpose ----------------
template<int C, int W>
__global__ __launch_bounds__(256) void transpose_k(const float* __restrict__ src,
                                                   bf16* __restrict__ dst) {
  constexpr int HW = W * W;
  int b = blockIdx.z;
  int hw0 = blockIdx.x * 64, c0 = blockIdx.y * 64;
  __shared__ bf16 tile[64][72];   // [hw_local][c_local]
  int t = threadIdx.x;
  {
    int cl = t >> 2, h0 = (t & 3) * 16;
    const float* sp = src + (long)(b * C + c0 + cl) * HW + hw0 + h0;
    #pragma unroll
    for (int k = 0; k < 16; k += 4) {
      float4 v = *(const float4*)(sp + k);
      tile[h0 + k + 0][cl] = __float2bfloat16(v.x);
      tile[h0 + k + 1][cl] = __float2bfloat16(v.y);
      tile[h0 + k + 2][cl] = __float2bfloat16(v.z);
      tile[h0 + k + 3][cl] = __float2bfloat16(v.w);
    }
  }
  __syncthreads();
  {
    int hwl = t >> 2, cc = (t & 3) * 16;
    bf16* dp = dst + ((long)b * HW + hw0 + hwl) * C + c0 + cc;
    #pragma unroll
    for (int k = 0; k < 16; k += 2) {
      __hip_bfloat162 pr;
      pr.x = tile[hwl][cc + k];
      pr.y = tile[hwl][cc + k + 1];
      *(__hip_bfloat162*)(dp + k) = pr;
    }
  }
}

// ---------------- sampling from NHWC bf16 ----------------
__device__ __forceinline__ float blo(u32 r) { return __uint_as_float(r << 16); }
__device__ __forceinline__ float bhi(u32 r) { return __uint_as_float(r & 0xffff0000u); }

template<int C, int W>
__device__ __forceinline__ void proc2(const bf16* __restrict__ T, int b,
    const float* MX, const float* MY, bf16* __restrict__ Sb, int koff, int t) {
  constexpr int C2 = C / 2, HW = W * W;
  const bf16* Tb = T + (long)b * HW * C;
  for (int idx = t; idx < 16 * C2; idx += 256) {
    int q = idx / C2, c2 = idx % C2;          // C2 pow2 -> shifts
    float x = MX[q], y = MY[q];
    float fx = fminf(fmaxf(x * ((float)W / 256.f) - 0.5f, 0.f), (float)(W - 1));
    float fy = fminf(fmaxf(y * ((float)W / 256.f) - 0.5f, 0.f), (float)(W - 1));
    float x0f = floorf(fx), y0f = floorf(fy);
    float wx = fx - x0f, wy = fy - y0f;
    int x0 = (int)x0f, y0 = (int)y0f;
    int x1 = min(x0 + 1, W - 1), y1 = min(y0 + 1, W - 1);
    u32 r00 = *(const u32*)&Tb[(y0 * W + x0) * C + 2 * c2];
    u32 r01 = *(const u32*)&Tb[(y0 * W + x1) * C + 2 * c2];
    u32 r10 = *(const u32*)&Tb[(y1 * W + x0) * C + 2 * c2];
    u32 r11 = *(const u32*)&Tb[(y1 * W + x1) * C + 2 * c2];
    float w00 = (1.f - wx) * (1.f - wy), w01 = wx * (1.f - wy);
    float w10 = (1.f - wx) * wy,        w11 = wx * wy;
    float vlo = blo(r00) * w00 + blo(r01) * w01 + blo(r10) * w10 + blo(r11) * w11;
    float vhi = bhi(r00) * w00 + bhi(r01) * w01 + bhi(r10) * w10 + bhi(r11) * w11;
    __hip_bfloat162 pr;
    pr.x = __float2bfloat16(vlo);
    pr.y = __float2bfloat16(vhi);
    *(__hip_bfloat162*)&Sb[(long)q * LAT_ + koff + 2 * c2] = pr;
  }
}

__global__ __launch_bounds__(256) void sample3_k(
    const bf16* __restrict__ T0, const bf16* __restrict__ T1, const bf16* __restrict__ T2,
    const bf16* __restrict__ T3, const bf16* __restrict__ T4, const bf16* __restrict__ T5,
    const float* __restrict__ P, bf16* __restrict__ Sball) {
  int b = blockIdx.y, p0 = blockIdx.x * 16, t = threadIdx.x;
  __shared__ float Px[32], Py[32], MX[16], MY[16];
  if (t < 32) { Px[t] = P[(b * 32 + t) * 2]; Py[t] = P[(b * 32 + t) * 2 + 1]; }
  __syncthreads();
  if (t < 16) {
    int m = p0 + t;
    float x, y;
    if (m < 32) { x = Px[m]; y = Py[m]; }
    else { int ij = m - 32, i = ij >> 5, j = ij & 31;
           x = 0.5f * (Px[i] + Px[j]); y = 0.5f * (Py[i] + Py[j]); }
    MX[t] = x; MY[t] = y;
  }
  __syncthreads();
  bf16* Sb = Sball + ((long)b * 1056 + p0) * LAT_;
  proc2<64, 128>(T0, b, MX, MY, Sb, 0,    t);
  proc2<64, 64 >(T1, b, MX, MY, Sb, 64,   t);
  proc2<128, 32>(T2, b, MX, MY, Sb, 128,  t);
  proc2<256, 16>(T3, b, MX, MY, Sb, 256,  t);
  proc2<512, 8 >(T4, b, MX, MY, Sb, 512,  t);
  for (int idx = t; idx < 16 * 256; idx += 256) {           // f5: direct copy
    int q = idx >> 8, c2 = idx & 255;
    *(__hip_bfloat162*)&Sb[(long)q * LAT_ + 1024 + 2 * c2] =
        *(const __hip_bfloat162*)&T5[b * 512 + 2 * c2];
  }
}

// ---------------- node GEMM: A4[b][32][2048] ----------------
__global__ __launch_bounds__(256) void nodegemm_k(
    const bf16* __restrict__ Sball, const bf16* __restrict__ Wp, float* __restrict__ A4) {
  int b = blockIdx.y;
  int n0 = blockIdx.x * 64;
  int t = threadIdx.x, w = t >> 6, lane = t & 63;
  int nn = n0 + w * 16;
  int frow = lane & 15, fko = (lane >> 4) * 8;
  const bf16* Ab = Sball + (long)b * 1056 * LAT_;
  f32x4 acc[2] = {};
  for (int kb = 0; kb < LAT_; kb += 32) {
    short8 bq = *(const short8*)&Wp[(long)(nn + frow) * LAT_ + kb + fko];
    #pragma unroll
    for (int i = 0; i < 2; ++i) {
      short8 aq = *(const short8*)&Ab[(long)(i * 16 + frow) * LAT_ + kb + fko];
      acc[i] = __builtin_amdgcn_mfma_f32_16x16x32_bf16(aq, bq, acc[i], 0, 0, 0);
    }
  }
  #pragma unroll
  for (int i = 0; i < 2; ++i)
    #pragma unroll
    for (int r = 0; r < 4; ++r) {
      int m = i * 16 + (lane >> 4) * 4 + r;
      int n = nn + (lane & 15);
      A4[(long)b * 65536 + m * 2048 + n] = acc[i][r];
    }
}

// ---------------- big MFMA GEMM (m97 structure, glds staging) ----------------
// MODE 0 edge:  A=Sb edges (lda 1536), B=WpE (N=1024: g|p), K=1536
//   epi: v=acc+ib+A4i+A4j -> XFh bf16; DH = bf16(relu(bn(v)))
// MODE 1 chorus (z=16: b,net): A=DH net-half (lda 1024), B=cw, K=512
//   epi: v=acc+cb+XFh resid -> net0: YgF fp32 ; net1: Yp16 bf16
template<int MODE>
__global__ __launch_bounds__(256) void mgemmB_k(
    const bf16* __restrict__ Abase, const bf16* __restrict__ B0, const bf16* __restrict__ B1,
    const float* __restrict__ bnp, const float* __restrict__ A4,
    bf16* __restrict__ XFh, bf16* __restrict__ DH,
    float* __restrict__ YgF, bf16* __restrict__ Yp16) {
  int m0 = blockIdx.x * 128;
  int n0 = blockIdx.y * 128;
  int b, net = 0, lda, K, ldb;
  const bf16 *A, *Bw;
  if (MODE == 0) {
    b = blockIdx.z;
    A = Abase + (long)b * 1056 * LAT_ + 32 * LAT_; lda = LAT_; K = LAT_;
    Bw = B0; ldb = LAT_;
  } else {
    int z = blockIdx.z; b = z >> 1; net = z & 1;
    A = Abase + (long)b * 1024 * 1024 + net * 512; lda = 1024; K = 512;
    Bw = net ? B1 : B0; ldb = 512;
  }
  __shared__ bf16 Ash[128 * 32];
  __shared__ bf16 Bsh[128 * 32];
  int t = threadIdx.x, w = t >> 6, lane = t & 63;
  int mh = (w & 1) * 64, nh = (w >> 1) * 64;
  int frow = lane & 15, fko = (lane >> 4) * 8;
  int lrow = lane >> 2, lko = (lane & 3) * 8;
  f32x4 acc[4][4] = {};
  for (int kb = 0; kb < K; kb += 32) {
    #pragma unroll
    for (int q = 0; q < 2; ++q) {
      int ra = q * 64 + w * 16 + lrow;
      glds16(&A[(long)(m0 + ra) * lda + kb + lko],  &Ash[ra * 32 + lko]);
      glds16(&Bw[(long)(n0 + ra) * ldb + kb + lko], &Bsh[ra * 32 + lko]);
    }
    __syncthreads();
    short8 af[4], bq[4];
    #pragma unroll
    for (int i = 0; i < 4; ++i) af[i] = *(const short8*)&Ash[(mh + i * 16 + frow) * 32 + fko];
    #pragma unroll
    for (int j = 0; j < 4; ++j) bq[j] = *(const short8*)&Bsh[(nh + j * 16 + frow) * 32 + fko];
    #pragma unroll
    for (int i = 0; i < 4; ++i)
      #pragma unroll
      for (int j = 0; j < 4; ++j)
        acc[i][j] = __builtin_amdgcn_mfma_f32_16x16x32_bf16(af[i], bq[j], acc[i][j], 0, 0, 0);
    __syncthreads();
  }
  #pragma unroll
  for (int i = 0; i < 4; ++i) {
    #pragma unroll
    for (int j = 0; j < 4; ++j) {
      #pragma unroll
      for (int r = 0; r < 4; ++r) {
        int m = m0 + mh + i * 16 + (lane >> 4) * 4 + r;
        int n = n0 + nh + j * 16 + (lane & 15);
        float v = acc[i][j][r];
        if (MODE == 0) {
          int nt = n >> 9, nn2 = n & 511;
          v += bnp[2048 + n]
             + A4[((long)b * 32 + (m >> 5)) * 2048 + nt * 1024 + nn2]
             + A4[((long)b * 32 + (m & 31)) * 2048 + nt * 1024 + 512 + nn2];
          XFh[((long)b * 1024 + m) * 1024 + n] = __float2bfloat16(v);
          float d = fmaxf(fmaf(v, bnp[nt * 1024 + nn2], bnp[nt * 1024 + 512 + nn2]), 0.f);
          DH[((long)b * 1024 + m) * 1024 + n] = __float2bfloat16(d);
        } else {
          v += bnp[3072 + net * 512 + n]
             + __bfloat162float(XFh[((long)b * 1024 + m) * 1024 + net * 512 + n]);
          if (net) Yp16[((long)b * 1024 + m) * 512 + n] = __float2bfloat16(v);
          else     YgF[((long)b * 1024 + m) * 512 + n] = v;
        }
      }
    }
  }
}

// ---------------- outro: PR[b][1024][64] = Yp16 @ p_ow^T + p_ob ----------------
__global__ __launch_bounds__(256) void outro_k(
    const bf16* __restrict__ A, const bf16* __restrict__ Bw,
    const float* __restrict__ bias, float* __restrict__ PR) {
  int b = blockIdx.z;
  const bf16* Ab = A + (long)b * 1024 * 512;
  int m0 = blockIdx.x * 128;
  __shared__ bf16 Ash[128][40];
  __shared__ bf16 Bsh[64][40];
  int t = threadIdx.x, w = t >> 6, lane = t & 63;
  int mq = w * 32;
  int frow = lane & 15, fko = (lane >> 4) * 8;
  f32x4 acc[2][4] = {};
  for (int kb = 0; kb < 512; kb += 32) {
    #pragma unroll
    for (int q = 0; q < 2; ++q) {
      int flat = q * 256 + t;
      int r = flat >> 2, ko = (flat & 3) * 8;
      *(uint4*)&Ash[r][ko] = *(const uint4*)&Ab[(long)(m0 + r) * 512 + kb + ko];
    }
    { int r = t >> 2, ko = (t & 3) * 8;
      *(uint4*)&Bsh[r][ko] = *(const uint4*)&Bw[(long)r * 512 + kb + ko]; }
    __syncthreads();
    short8 af[2], bq[4];
    #pragma unroll
    for (int i = 0; i < 2; ++i) af[i] = *(const short8*)&Ash[mq + i * 16 + frow][fko];
    #pragma unroll
    for (int j = 0; j < 4; ++j) bq[j] = *(const short8*)&Bsh[j * 16 + frow][fko];
    #pragma unroll
    for (int i = 0; i < 2; ++i)
      #pragma unroll
      for (int j = 0; j < 4; ++j)
        acc[i][j] = __builtin_amdgcn_mfma_f32_16x16x32_bf16(af[i], bq[j], acc[i][j], 0, 0, 0);
    __syncthreads();
  }
  #pragma unroll
  for (int i = 0; i < 2; ++i)
    #pragma unroll
    for (int j = 0; j < 4; ++j)
      #pragma unroll
      for (int r = 0; r < 4; ++r) {
        int m = m0 + mq + i * 16 + (lane >> 4) * 4 + r;
        int n = j * 16 + (lane & 15);
        PR[((long)b * 1024 + m) * 64 + n] = acc[i][j][r] + bias[n];
      }
}

// ---------------- final: wave per (b, ij) ----------------
__global__ __launch_bounds__(256) void final2_k(
    const float* __restrict__ Yg, const float* __restrict__ PR,
    const float* __restrict__ g_ow, const float* __restrict__ g_ob,
    const int* __restrict__ n, float* __restrict__ out) {
  int gw = blockIdx.x * 4 + (threadIdx.x >> 6);
  int lane = threadIdx.x & 63;
  int b = gw >> 10, ij = gw & 1023;
  const float* yrow = Yg + ((long)b * 1024 + ij) * 512;
  float g = 0.f;
  #pragma unroll
  for (int q = 0; q < 8; ++q) { int o = q * 64 + lane; g = fmaf(g_ow[o], yrow[o], g); }
  #pragma unroll
  for (int off = 32; off; off >>= 1) g += __shfl_down(g, off);
  g = __shfl(g, 0) + g_ob[0];
  float gate = 1.f / (1.f + expf(-g));
  int i = ij >> 5, j = ij & 31, nb = n[b];
  float maskv = (i < nb && j < nb) ? 1.f : 0.f;
  float v = PR[((long)b * 1024 + ij) * 64 + lane];
  float ss = v * v;
  #pragma unroll
  for (int off = 32; off; off >>= 1) ss += __shfl_down(ss, off);
  ss = __shfl(ss, 0);
  float scale = gate * maskv / fmaxf(sqrtf(ss), 1e-12f);
  out[((long)b * 64 + lane) * 1024 + ij] = v * scale;
}

extern "C" void kernel_launch(void* const* d_in, const int* in_sizes, int n_in,
                              void* d_out, int out_size, void* d_ws, size_t ws_size,
                              hipStream_t stream) {
  const float* f0 = (const float*)d_in[0];
  const float* f1 = (const float*)d_in[1];
  const float* f2 = (const float*)d_in[2];
  const float* f3 = (const float*)d_in[3];
  const float* f4 = (const float*)d_in[4];
  const float* f5 = (const float*)d_in[5];
  const float* P  = (const float*)d_in[6];
  const int*   n  = (const int*)d_in[7];
  const float *g_iw=(const float*)d_in[8],  *g_ib=(const float*)d_in[9],
              *g_bg=(const float*)d_in[10], *g_bb=(const float*)d_in[11],
              *g_bm=(const float*)d_in[12], *g_bv=(const float*)d_in[13],
              *g_cw=(const float*)d_in[14], *g_cb=(const float*)d_in[15],
              *g_ow=(const float*)d_in[16], *g_ob=(const float*)d_in[17];
  const float *p_iw=(const float*)d_in[18], *p_ib=(const float*)d_in[19],
              *p_bg=(const float*)d_in[20], *p_bb=(const float*)d_in[21],
              *p_bm=(const float*)d_in[22], *p_bv=(const float*)d_in[23],
              *p_cw=(const float*)d_in[24], *p_cb=(const float*)d_in[25],
              *p_ow=(const float*)d_in[26], *p_ob=(const float*)d_in[27];
  float* out = (float*)d_out;
  char* wsb = (char*)d_ws;

  // workspace (byte offsets)
  bf16*  Sb   = (bf16*)(wsb + 0);                    // 25,952,256
  bf16*  Wp   = (bf16*)(wsb + 25952256);             //  9,437,184
  bf16*  CWp  = (bf16*)(wsb + 35389440);             //  1,122,304
  float* bnp  = (float*)(wsb + 36511744);            //     16,384
  float* A4   = (float*)(wsb + 36528128);            //  2,097,152
  bf16*  XFh  = (bf16*)(wsb + 38625280);             // 16,777,216
  bf16*  DH   = (bf16*)(wsb + 55402496);             // 16,777,216
  bf16*  Yp16 = (bf16*)(wsb + 72179712);             //  8,388,608 -> ends 80,568,320
  // overlays (dead regions)
  bf16*  T0 = (bf16*)(wsb + 38625280);               // T* overlay XFh+DH (dead before edge)
  bf16*  T1 = (bf16*)(wsb + 55402496);
  bf16*  T2 = (bf16*)(wsb + 59596800);
  bf16*  T3 = (bf16*)(wsb + 61693952);
  bf16*  T4 = (bf16*)(wsb + 62742528);
  float* YgF = (float*)(wsb + 0);                    // overlay Sb (dead after edge)
  float* PR  = (float*)(wsb + 36528128);             // overlay A4 (dead after edge)

  bf16* gcw16 = CWp;
  bf16* pcw16 = CWp + 262144;
  bf16* pow16 = CWp + 524288;
  bf16* T5    = CWp + 557056;
  bf16* WpE   = Wp + (long)2048 * LAT_;

  conv1536_k<<<dim3(3072, 6), 256, 0, stream>>>(g_iw, p_iw, Wp);
  conv512_k<<<dim3(1024, 4), 256, 0, stream>>>(g_cw, p_cw, p_ow, f5, CWp);
  bnconst2_k<<<dim3(2), 256, 0, stream>>>(g_bg, g_bb, g_bm, g_bv, p_bg, p_bb, p_bm, p_bv,
                                          g_ib, p_ib, g_cb, p_cb, bnp);
  transpose_k<64, 128><<<dim3(256, 1, 8), 256, 0, stream>>>(f0, T0);
  transpose_k<64, 64 ><<<dim3(64, 1, 8),  256, 0, stream>>>(f1, T1);
  transpose_k<128, 32><<<dim3(16, 2, 8),  256, 0, stream>>>(f2, T2);
  transpose_k<256, 16><<<dim3(4, 4, 8),   256, 0, stream>>>(f3, T3);
  transpose_k<512, 8 ><<<dim3(1, 8, 8),   256, 0, stream>>>(f4, T4);

  sample3_k<<<dim3(66, 8), 256, 0, stream>>>(T0, T1, T2, T3, T4, T5, P, Sb);
  nodegemm_k<<<dim3(32, 8), 256, 0, stream>>>(Sb, Wp, A4);

  // merged edge GEMM (g|p), N=1024
  mgemmB_k<0><<<dim3(8, 8, 8), 256, 0, stream>>>(Sb, WpE, nullptr, bnp, A4,
                                                 XFh, DH, nullptr, nullptr);
  // merged chorus (z = b*2 + net)
  mgemmB_k<1><<<dim3(8, 4, 16), 256, 0, stream>>>(DH, gcw16, pcw16, bnp, nullptr,
                                                  XFh, nullptr, YgF, Yp16);
  // outro
  outro_k<<<dim3(8, 1, 8), 256, 0, stream>>>(Yp16, pow16, p_ob, PR);
  // gate + normalize + mask
  final2_k<<<dim3(2048), 256, 0, stream>>>(YgF, PR, g_ow, g_ob, n, out);
}